// Round 6
// baseline (244.329 us; speedup 1.0000x reference)
//
#include <hip/hip_runtime.h>
#include <hip/hip_bf16.h>

#define T_SEQ 2048
#define DMODEL 1024
#define NH 16
#define HD 64

typedef __attribute__((ext_vector_type(8))) short bf16x8;
typedef __attribute__((ext_vector_type(4))) float f32x4;
typedef __attribute__((ext_vector_type(16))) float f32x16;

__device__ __forceinline__ f32x4 mfma16(bf16x8 a, bf16x8 b, f32x4 c) {
  return __builtin_amdgcn_mfma_f32_16x16x32_bf16(a, b, c, 0, 0, 0);
}
__device__ __forceinline__ f32x16 mfma32(bf16x8 a, bf16x8 b, f32x16 c) {
  return __builtin_amdgcn_mfma_f32_32x32x16_bf16(a, b, c, 0, 0, 0);
}

__device__ __forceinline__ unsigned short f2b(float f) {
  return __builtin_bit_cast(unsigned short, __float2bfloat16(f));
}
__device__ __forceinline__ unsigned packpair(float lo, float hi) {
  return (unsigned)f2b(lo) | ((unsigned)f2b(hi) << 16);  // v_cvt_pk_bf16_f32
}

// async global->LDS, 16B per lane; LDS dest = wave-uniform base + lane*16
#define GLOAD16(g, l)                                                          \
  __builtin_amdgcn_global_load_lds(                                            \
      (const __attribute__((address_space(1))) unsigned int*)(g),              \
      (__attribute__((address_space(3))) unsigned int*)(l), 16, 0, 0)

// swap: a.hi <-> b.lo
#define PLSWAP(a, b) asm("v_permlane32_swap_b32 %0, %1" : "+v"(a), "+v"(b))

#define VMCNT0_BAR()                                                           \
  do {                                                                         \
    asm volatile("s_waitcnt vmcnt(0)" ::: "memory");                           \
    __builtin_amdgcn_s_barrier();                                              \
  } while (0)

// q scale folded with log2(e): hd^-0.5 * 1.4426950408889634
#define QSCALE 0.18033688011112043f

// ======================================================================
// fused fp32->bf16 conversion for all 5 tensors (4 elems/thread)
// ======================================================================
__global__ __launch_bounds__(256)
void cvt_all(const float* __restrict__ x,  const float* __restrict__ wq,
             const float* __restrict__ wk, const float* __restrict__ wv,
             const float* __restrict__ wo, unsigned short* __restrict__ xb,
             unsigned short* __restrict__ wqkv, unsigned short* __restrict__ wob) {
  const int g = blockIdx.x * 256 + threadIdx.x;   // 0 .. 2M-1
  const int M1 = 1 << 20, WG = 1 << 18;
  const float* src; unsigned short* dst; int off;
  if (g < M1)               { src = x;  dst = xb;             off = g; }
  else if (g < M1 + WG)     { src = wq; dst = wqkv;           off = g - M1; }
  else if (g < M1 + 2 * WG) { src = wk; dst = wqkv + M1;      off = g - M1 - WG; }
  else if (g < M1 + 3 * WG) { src = wv; dst = wqkv + 2 * M1;  off = g - M1 - 2 * WG; }
  else                      { src = wo; dst = wob;            off = g - M1 - 3 * WG; }
  const float4 v = ((const float4*)src)[off];
  ushort4 o;
  o.x = f2b(v.x); o.y = f2b(v.y); o.z = f2b(v.z); o.w = f2b(v.w);
  ((ushort4*)dst)[off] = o;
}

// ======================================================================
// bf16 GEMM: C[m,n] = sum_k A[m,k]*B[n,k].  BM=BN=128, BK=32, 256 thr,
// 2-phase double-buffered pipeline: STAGE(next) -> ds_read+MFMA(cur) ->
// vmcnt(0)+s_barrier (one barrier per K-step; loads fly under compute).
// CMODE 3 epilogue additionally applies RoPE to Q/K (pair via shfl_xor 1)
// and pre-scales Q by QSCALE (softmax later runs in exp2 domain).
// ======================================================================
template<int AMODE, int CMODE>
__global__ __launch_bounds__(256)
void gemm_bf16(const unsigned short* __restrict__ A, const unsigned short* __restrict__ B,
               unsigned short* __restrict__ Cq, unsigned short* __restrict__ Cv,
               float* __restrict__ Cf, const float* __restrict__ fcg,
               int M, int N, int K) {
  __shared__ __align__(16) unsigned short As[2][4096];  // 2 x (128 x 32) bf16
  __shared__ __align__(16) unsigned short Bs[2][4096];
  const int tid  = threadIdx.x;
  const int wid  = tid >> 6, lane = tid & 63;
  const int lg   = lane >> 4, lr = lane & 15;
  const int wr   = wid >> 1, wc = wid & 1;
  const int m0   = blockIdx.y * 128, n0 = blockIdx.x * 128;

  auto stage = [&](unsigned short* asb, unsigned short* bsb, int k0) {
    #pragma unroll
    for (int i = 0; i < 2; ++i) {
      const int c = i * 256 + wid * 64 + lane;   // linear 16B chunk 0..511
      const int r = c >> 2, slot = c & 3, js = slot ^ (r & 3);
      const unsigned short* ga;
      if (AMODE == 0) ga = A + (m0 + r) * K + k0 + js * 8;
      else {
        const int m = m0 + r;
        ga = A + (((m >> 11) * NH + (k0 >> 6)) * T_SEQ + (m & 2047)) * HD + (k0 & 63) + js * 8;
      }
      GLOAD16(ga, (char*)asb + i * 4096 + wid * 1024);
      GLOAD16(B + (n0 + r) * K + k0 + js * 8, (char*)bsb + i * 4096 + wid * 1024);
    }
  };

  f32x4 acc[4][4];
  const f32x4 z = {0.f, 0.f, 0.f, 0.f};
  #pragma unroll
  for (int i = 0; i < 4; ++i)
    #pragma unroll
    for (int j = 0; j < 4; ++j) acc[i][j] = z;

  const int KT = K >> 5;
  stage(As[0], Bs[0], 0);
  VMCNT0_BAR();
  int cur = 0;
  for (int t = 0; t < KT; ++t) {
    if (t + 1 < KT) stage(As[cur ^ 1], Bs[cur ^ 1], (t + 1) * 32);

    bf16x8 af[4], bfr[4];
    #pragma unroll
    for (int f = 0; f < 4; ++f) {
      const int ra = wr * 64 + f * 16 + lr;
      af[f]  = *(const bf16x8*)((const char*)As[cur] + ra * 64 + ((lg ^ (ra & 3)) << 4));
      const int rb = wc * 64 + f * 16 + lr;
      bfr[f] = *(const bf16x8*)((const char*)Bs[cur] + rb * 64 + ((lg ^ (rb & 3)) << 4));
    }
    #pragma unroll
    for (int i = 0; i < 4; ++i)
      #pragma unroll
      for (int j = 0; j < 4; ++j)
        acc[i][j] = mfma16(af[i], bfr[j], acc[i][j]);

    VMCNT0_BAR();   // next tile landed; cur free for restage
    cur ^= 1;
  }

  // ---- epilogue.  C layout: col = lane&15, row = (lane>>4)*4 + reg ----
  #pragma unroll
  for (int i = 0; i < 4; ++i)
    #pragma unroll
    for (int j = 0; j < 4; ++j)
      #pragma unroll
      for (int reg = 0; reg < 4; ++reg) {
        const int m = m0 + wr * 64 + i * 16 + lg * 4 + reg;
        const int n = n0 + wc * 64 + j * 16 + lr;
        const float val = acc[i][j][reg];
        if (CMODE == 0) {
          Cf[m * N + n] = val;
        } else {
          const int b = m >> 11, t = m & 2047;
          if (n < 2048) {
            // fused RoPE: partner element lives in lane^1 (adjacent d)
            const float pv = __shfl_xor(val, 1);
            const int d = n & 63;
            const float co = fcg[t * 64 + (d & 62)];
            const float si = fcg[t * 64 + (d & 62) + 1];
            float outv = (d & 1) ? (pv * si + val * co) : (val * co - pv * si);
            if (n < 1024) outv *= QSCALE;   // Q pre-scale (exp2 domain)
            const int head = (n & 1023) >> 6;
            Cq[(n >> 10) * 4194304 + ((b * NH + head) * T_SEQ + t) * HD + d] = f2b(outv);
          } else {
            const int nv = n - 2048, head = nv >> 6, d = nv & 63;
            Cv[((b * NH + head) * HD + d) * T_SEQ + t] = f2b(val);
          }
        }
      }
}

// ======================================================================
// Swapped-operand 32x32 MFMA flash attention, 2-phase pipelined.
// Block = 4 waves x 32 q-rows = 128 q.  KV tile = 64 keys, double-buffered.
// S^T = K Q^T; softmax lane-local in exp2 domain with defer-max (T13);
// P->A-frag in-register (cvt_pk + permlane32_swap); O^T = V^T P^T.
// Q pre-scaled by 0.125*log2e.  Grid 512 = 8 XCDs x 4 bh x 16 qb heavy-first.
// ======================================================================
__global__ __launch_bounds__(256)
void attn_kernel(const unsigned short* __restrict__ Q, const unsigned short* __restrict__ K,
                 const unsigned short* __restrict__ V, unsigned short* __restrict__ AO) {
  __shared__ __align__(16) char Ks[2][8192];   // [key][128B: d-chunks swizzled]
  __shared__ __align__(16) char Vs[2][8192];   // [d][128B: key-chunks swizzled]
  const int tid = threadIdx.x;
  const int wid = tid >> 6, lane = tid & 63;
  const int l31 = lane & 31, hi = lane >> 5;

  const int id  = blockIdx.x;          // 0..511
  const int xcd = id & 7, j = id >> 3;
  const int bh  = xcd * 4 + (j & 3);
  const int qb  = 15 - (j >> 2);       // heavy-first
  const int base = bh * (T_SEQ * HD);
  const int qw  = qb * 128 + wid * 32;
  const int q   = qw + l31;

  auto stage = [&](char* ksb, char* vsb, int k0) {
    #pragma unroll
    for (int i = 0; i < 2; ++i) {
      const int c = i * 256 + wid * 64 + lane;   // linear chunk 0..511
      const int r = c >> 3, sg = c & 7, js = sg ^ (r & 7);
      GLOAD16(K + base + (k0 + r) * HD + js * 8, ksb + i * 4096 + wid * 1024);
      GLOAD16(V + base + r * T_SEQ + k0 + js * 8, vsb + i * 4096 + wid * 1024);
    }
  };

  // Q fragments (B-operand): qfr[ds] = Q[q][ds*16 + hi*8 .. +7]
  bf16x8 qfr[4];
  #pragma unroll
  for (int ds = 0; ds < 4; ++ds)
    qfr[ds] = *(const bf16x8*)(Q + base + q * HD + ds * 16 + hi * 8);

  f32x16 o[2];
  #pragma unroll
  for (int r = 0; r < 16; ++r) { o[0][r] = 0.f; o[1][r] = 0.f; }
  float m_run = -1e30f, l_run = 0.f;

  const int ntiles = 2 * qb + 2;
  stage(Ks[0], Vs[0], 0);
  VMCNT0_BAR();
  int cur = 0;

  for (int kt = 0; kt < ntiles; ++kt) {
    const int k0 = kt * 64;
    if (kt + 1 < ntiles) stage(Ks[cur ^ 1], Vs[cur ^ 1], (kt + 1) * 64);

    if (k0 <= qw + 31) {   // wave-uniform: any unmasked work in this tile?
      const char* Kc = Ks[cur];
      const char* Vc = Vs[cur];
      // ---- S^T = K Q^T : two 32-key blocks ----
      f32x16 s0, s1;
      #pragma unroll
      for (int r = 0; r < 16; ++r) { s0[r] = 0.f; s1[r] = 0.f; }
      __builtin_amdgcn_s_setprio(1);
      #pragma unroll
      for (int ds = 0; ds < 4; ++ds) {
        const int sg = ds * 2 + hi;
        const int key0 = l31, key1 = 32 + l31;
        const bf16x8 kf0 = *(const bf16x8*)(Kc + key0 * 128 + ((sg ^ (key0 & 7)) << 4));
        const bf16x8 kf1 = *(const bf16x8*)(Kc + key1 * 128 + ((sg ^ (key1 & 7)) << 4));
        s0 = mfma32(kf0, qfr[ds], s0);
        s1 = mfma32(kf1, qfr[ds], s1);
      }
      __builtin_amdgcn_s_setprio(0);

      // ---- causal mask (diagonal tiles only) ----
      if (k0 + 63 > qw) {
        #pragma unroll
        for (int r = 0; r < 16; ++r) {
          const int kr = (r & 3) + 8 * (r >> 2) + 4 * hi;
          if (k0 + kr > q)      s0[r] = -1e30f;
          if (k0 + 32 + kr > q) s1[r] = -1e30f;
        }
      }

      // ---- lane-local online softmax, exp2 domain, defer-max ----
      float mx = s0[0];
      #pragma unroll
      for (int r = 1; r < 16; ++r) mx = fmaxf(mx, s0[r]);
      #pragma unroll
      for (int r = 0; r < 16; ++r) mx = fmaxf(mx, s1[r]);
      mx = fmaxf(mx, __shfl_xor(mx, 32));
      if (!__all(mx <= m_run + 11.5f)) {   // rescale only when max grew
        const float mnew = fmaxf(m_run, mx);
        const float alpha = exp2f(m_run - mnew);
        m_run = mnew;
        l_run *= alpha;
        #pragma unroll
        for (int r = 0; r < 16; ++r) { o[0][r] *= alpha; o[1][r] *= alpha; }
      }
      float sumA = 0.f, sumB = 0.f;
      #pragma unroll
      for (int r = 0; r < 16; ++r) {
        s0[r] = exp2f(s0[r] - m_run); sumA += s0[r];
        s1[r] = exp2f(s1[r] - m_run); sumB += s1[r];
      }
      float sum = sumA + sumB;
      sum += __shfl_xor(sum, 32);
      l_run += sum;

      // ---- P -> bf16 A/B-frag in-register, then O^T += V^T P^T ----
      #pragma unroll
      for (int ks = 0; ks < 4; ++ks) {
        const f32x16 pt = (ks < 2) ? s0 : s1;
        const int m = 8 * (ks & 1);
        unsigned wA = packpair(pt[m + 0], pt[m + 1]);
        unsigned wB = packpair(pt[m + 2], pt[m + 3]);
        unsigned wC = packpair(pt[m + 4], pt[m + 5]);
        unsigned wD = packpair(pt[m + 6], pt[m + 7]);
        PLSWAP(wA, wC);
        PLSWAP(wB, wD);
        uint4 uw; uw.x = wA; uw.y = wB; uw.z = wC; uw.w = wD;
        const bf16x8 pf = __builtin_bit_cast(bf16x8, uw);
        __builtin_amdgcn_s_setprio(1);
        #pragma unroll
        for (int db = 0; db < 2; ++db) {
          const int d = db * 32 + l31;
          const int sg = ks * 2 + hi;
          const bf16x8 vf = *(const bf16x8*)(Vc + d * 128 + ((sg ^ (d & 7)) << 4));
          o[db] = mfma32(vf, pf, o[db]);
        }
        __builtin_amdgcn_s_setprio(0);
      }
    }

    VMCNT0_BAR();   // next tile landed; cur free for restage
    cur ^= 1;
  }

  // ---- epilogue: O^T/l -> AO (B,H,T,hd) ----
  const float inv = 1.f / l_run;
  #pragma unroll
  for (int db = 0; db < 2; ++db)
    #pragma unroll
    for (int t = 0; t < 4; ++t) {
      ushort4 pk;
      pk.x = f2b(o[db][4 * t + 0] * inv);
      pk.y = f2b(o[db][4 * t + 1] * inv);
      pk.z = f2b(o[db][4 * t + 2] * inv);
      pk.w = f2b(o[db][4 * t + 3] * inv);
      const int d = db * 32 + 8 * t + 4 * hi;
      *(ushort4*)(AO + base + q * HD + d) = pk;
    }
}

// ======================================================================
extern "C" void kernel_launch(void* const* d_in, const int* in_sizes, int n_in,
                              void* d_out, int out_size, void* d_ws, size_t ws_size,
                              hipStream_t stream) {
  const float* x  = (const float*)d_in[0];
  const float* wq = (const float*)d_in[1];
  const float* wk = (const float*)d_in[2];
  const float* wv = (const float*)d_in[3];
  const float* wo = (const float*)d_in[4];
  const float* fc = (const float*)d_in[5];
  float* out = (float*)d_out;

  const int ME = 1 << 20;
  unsigned short* W    = (unsigned short*)d_ws;
  unsigned short* xb   = W;               // 4M  x bf16
  unsigned short* wqkv = W + 4 * ME;      // 3M  [wq;wk;wv] bf16
  unsigned short* wob  = W + 7 * ME;      // 1M
  unsigned short* Qb   = W + 8 * ME;      // 4M  (B,H,T,hd), pre-scaled+RoPE'd
  unsigned short* Kb   = W + 12 * ME;     // 4M  (B,H,T,hd), RoPE'd
  unsigned short* Vt   = W + 16 * ME;     // 4M  (B,H,hd,T)
  unsigned short* AO   = W + 20 * ME;     // 4M  (B,H,T,hd)

  // ---- fp32 -> bf16 (single fused kernel) ----
  hipLaunchKernelGGL(cvt_all, dim3(8192), dim3(256), 0, stream,
                     x, wq, wk, wv, wo, xb, wqkv, wob);

  // ---- fused QKV projection + RoPE + Q pre-scale ----
  hipLaunchKernelGGL((gemm_bf16<0, 3>), dim3(24, 32), dim3(256), 0, stream,
                     xb, wqkv, Qb, Vt, (float*)nullptr, fc, 4096, 3072, 1024);

  // ---- attention ----
  hipLaunchKernelGGL(attn_kernel, dim3(512), dim3(256), 0, stream, Qb, Kb, Vt, AO);

  // ---- output projection ----
  hipLaunchKernelGGL((gemm_bf16<1, 0>), dim3(8, 32), dim3(256), 0, stream,
                     AO, wob, (unsigned short*)nullptr, (unsigned short*)nullptr,
                     out, (const float*)nullptr, 4096, 1024, 1024);
}

// Round 7
// 229.758 us; speedup vs baseline: 1.0634x; 1.0634x over previous
//
#include <hip/hip_runtime.h>
#include <hip/hip_bf16.h>

#define T_SEQ 2048
#define DMODEL 1024
#define NH 16
#define HD 64

typedef __attribute__((ext_vector_type(8))) short bf16x8;
typedef __attribute__((ext_vector_type(4))) float f32x4;
typedef __attribute__((ext_vector_type(16))) float f32x16;

__device__ __forceinline__ f32x4 mfma16(bf16x8 a, bf16x8 b, f32x4 c) {
  return __builtin_amdgcn_mfma_f32_16x16x32_bf16(a, b, c, 0, 0, 0);
}
__device__ __forceinline__ f32x16 mfma32(bf16x8 a, bf16x8 b, f32x16 c) {
  return __builtin_amdgcn_mfma_f32_32x32x16_bf16(a, b, c, 0, 0, 0);
}

__device__ __forceinline__ unsigned short f2b(float f) {
  return __builtin_bit_cast(unsigned short, __float2bfloat16(f));
}
__device__ __forceinline__ unsigned packpair(float lo, float hi) {
  return (unsigned)f2b(lo) | ((unsigned)f2b(hi) << 16);  // v_cvt_pk_bf16_f32
}

// async global->LDS, 16B per lane; LDS dest = wave-uniform base + lane*16
#define GLOAD16(g, l)                                                          \
  __builtin_amdgcn_global_load_lds(                                            \
      (const __attribute__((address_space(1))) unsigned int*)(g),              \
      (__attribute__((address_space(3))) unsigned int*)(l), 16, 0, 0)

// swap: a.hi <-> b.lo
#define PLSWAP(a, b) asm("v_permlane32_swap_b32 %0, %1" : "+v"(a), "+v"(b))

#define VMCNT0_BAR()                                                           \
  do {                                                                         \
    asm volatile("s_waitcnt vmcnt(0)" ::: "memory");                           \
    __builtin_amdgcn_s_barrier();                                              \
  } while (0)

// q pre-scale: hd^-0.5 = 0.125 (plain; softmax uses __expf)
#define QSCALE 0.125f

// ======================================================================
// fused fp32->bf16 conversion for all 5 tensors (4 elems/thread)
// ======================================================================
__global__ __launch_bounds__(256)
void cvt_all(const float* __restrict__ x,  const float* __restrict__ wq,
             const float* __restrict__ wk, const float* __restrict__ wv,
             const float* __restrict__ wo, unsigned short* __restrict__ xb,
             unsigned short* __restrict__ wqkv, unsigned short* __restrict__ wob) {
  const int g = blockIdx.x * 256 + threadIdx.x;   // 0 .. 2M-1
  const int M1 = 1 << 20, WG = 1 << 18;
  const float* src; unsigned short* dst; int off;
  if (g < M1)               { src = x;  dst = xb;             off = g; }
  else if (g < M1 + WG)     { src = wq; dst = wqkv;           off = g - M1; }
  else if (g < M1 + 2 * WG) { src = wk; dst = wqkv + M1;      off = g - M1 - WG; }
  else if (g < M1 + 3 * WG) { src = wv; dst = wqkv + 2 * M1;  off = g - M1 - 2 * WG; }
  else                      { src = wo; dst = wob;            off = g - M1 - 3 * WG; }
  const float4 v = ((const float4*)src)[off];
  ushort4 o;
  o.x = f2b(v.x); o.y = f2b(v.y); o.z = f2b(v.z); o.w = f2b(v.w);
  ((ushort4*)dst)[off] = o;
}

// ======================================================================
// bf16 GEMM: C[m,n] = sum_k A[m,k]*B[n,k].  BM=BN=128, BK=32, 256 thr,
// 2-phase double-buffered pipeline (kept from r6: neutral-to-positive).
// CMODE 3 epilogue applies RoPE to Q/K (pair via shfl_xor 1) and
// pre-scales Q by 0.125.
// ======================================================================
template<int AMODE, int CMODE>
__global__ __launch_bounds__(256)
void gemm_bf16(const unsigned short* __restrict__ A, const unsigned short* __restrict__ B,
               unsigned short* __restrict__ Cq, unsigned short* __restrict__ Cv,
               float* __restrict__ Cf, const float* __restrict__ fcg,
               int M, int N, int K) {
  __shared__ __align__(16) unsigned short As[2][4096];  // 2 x (128 x 32) bf16
  __shared__ __align__(16) unsigned short Bs[2][4096];
  const int tid  = threadIdx.x;
  const int wid  = tid >> 6, lane = tid & 63;
  const int lg   = lane >> 4, lr = lane & 15;
  const int wr   = wid >> 1, wc = wid & 1;
  const int m0   = blockIdx.y * 128, n0 = blockIdx.x * 128;

  auto stage = [&](unsigned short* asb, unsigned short* bsb, int k0) {
    #pragma unroll
    for (int i = 0; i < 2; ++i) {
      const int c = i * 256 + wid * 64 + lane;   // linear 16B chunk 0..511
      const int r = c >> 2, slot = c & 3, js = slot ^ (r & 3);
      const unsigned short* ga;
      if (AMODE == 0) ga = A + (m0 + r) * K + k0 + js * 8;
      else {
        const int m = m0 + r;
        ga = A + (((m >> 11) * NH + (k0 >> 6)) * T_SEQ + (m & 2047)) * HD + (k0 & 63) + js * 8;
      }
      GLOAD16(ga, (char*)asb + i * 4096 + wid * 1024);
      GLOAD16(B + (n0 + r) * K + k0 + js * 8, (char*)bsb + i * 4096 + wid * 1024);
    }
  };

  f32x4 acc[4][4];
  const f32x4 z = {0.f, 0.f, 0.f, 0.f};
  #pragma unroll
  for (int i = 0; i < 4; ++i)
    #pragma unroll
    for (int j = 0; j < 4; ++j) acc[i][j] = z;

  const int KT = K >> 5;
  stage(As[0], Bs[0], 0);
  VMCNT0_BAR();
  int cur = 0;
  for (int t = 0; t < KT; ++t) {
    if (t + 1 < KT) stage(As[cur ^ 1], Bs[cur ^ 1], (t + 1) * 32);

    bf16x8 af[4], bfr[4];
    #pragma unroll
    for (int f = 0; f < 4; ++f) {
      const int ra = wr * 64 + f * 16 + lr;
      af[f]  = *(const bf16x8*)((const char*)As[cur] + ra * 64 + ((lg ^ (ra & 3)) << 4));
      const int rb = wc * 64 + f * 16 + lr;
      bfr[f] = *(const bf16x8*)((const char*)Bs[cur] + rb * 64 + ((lg ^ (rb & 3)) << 4));
    }
    #pragma unroll
    for (int i = 0; i < 4; ++i)
      #pragma unroll
      for (int j = 0; j < 4; ++j)
        acc[i][j] = mfma16(af[i], bfr[j], acc[i][j]);

    VMCNT0_BAR();   // next tile landed; cur free for restage
    cur ^= 1;
  }

  // ---- epilogue.  C layout: col = lane&15, row = (lane>>4)*4 + reg ----
  #pragma unroll
  for (int i = 0; i < 4; ++i)
    #pragma unroll
    for (int j = 0; j < 4; ++j)
      #pragma unroll
      for (int reg = 0; reg < 4; ++reg) {
        const int m = m0 + wr * 64 + i * 16 + lg * 4 + reg;
        const int n = n0 + wc * 64 + j * 16 + lr;
        const float val = acc[i][j][reg];
        if (CMODE == 0) {
          Cf[m * N + n] = val;
        } else {
          const int b = m >> 11, t = m & 2047;
          if (n < 2048) {
            // fused RoPE: partner element lives in lane^1 (adjacent d)
            const float pv = __shfl_xor(val, 1);
            const int d = n & 63;
            const float co = fcg[t * 64 + (d & 62)];
            const float si = fcg[t * 64 + (d & 62) + 1];
            float outv = (d & 1) ? (pv * si + val * co) : (val * co - pv * si);
            if (n < 1024) outv *= QSCALE;   // Q pre-scale
            const int head = (n & 1023) >> 6;
            Cq[(n >> 10) * 4194304 + ((b * NH + head) * T_SEQ + t) * HD + d] = f2b(outv);
          } else {
            const int nv = n - 2048, head = nv >> 6, d = nv & 63;
            Cv[((b * NH + head) * HD + d) * T_SEQ + t] = f2b(val);
          }
        }
      }
}

// ======================================================================
// Swapped-operand 32x32 MFMA flash attention (round-5 structure:
// single-buffered LDS, two __syncthreads per tile, __expf)
// + defer-max (T13, THR=8) + balanced qb pairing.
// Block = 4 waves x 32 q-rows = 128 q.  KV tile = 64 keys.
// S^T = K Q^T; softmax lane-local; P->A-frag in-register
// (cvt_pk + permlane32_swap); O^T = V^T P^T.  Q pre-scaled by 1/8.
// Grid 512 = 8 XCDs x 64; qb map pairs heavy/light per CU:
// j<32 -> qb 15..8, j>=32 -> qb 0..7 (co-resident pairs sum ~17 tiles).
// ======================================================================
__global__ __launch_bounds__(256)
void attn_kernel(const unsigned short* __restrict__ Q, const unsigned short* __restrict__ K,
                 const unsigned short* __restrict__ V, unsigned short* __restrict__ AO) {
  __shared__ __align__(16) char Ks[8192];   // [key 0..63][128B: d-chunks swizzled]
  __shared__ __align__(16) char Vs[8192];   // [d 0..63][128B: key-chunks swizzled]
  const int tid = threadIdx.x;
  const int wid = tid >> 6, lane = tid & 63;
  const int l31 = lane & 31, hi = lane >> 5;

  const int id  = blockIdx.x;          // 0..511
  const int xcd = id & 7, j = id >> 3; // consecutive ids round-robin XCDs
  const int bh  = xcd * 4 + (j & 3);
  const int qb  = (j < 32) ? (15 - (j >> 2)) : ((j >> 2) - 8);
  const int base = bh * (T_SEQ * HD);
  const int qw  = qb * 128 + wid * 32; // wave's first q row
  const int q   = qw + l31;            // this lane's q row

  // Q fragments (B-operand): qfr[ds] = Q[q][ds*16 + hi*8 .. +7]
  bf16x8 qfr[4];
  #pragma unroll
  for (int ds = 0; ds < 4; ++ds)
    qfr[ds] = *(const bf16x8*)(Q + base + q * HD + ds * 16 + hi * 8);

  f32x16 o[2];
  #pragma unroll
  for (int r = 0; r < 16; ++r) { o[0][r] = 0.f; o[1][r] = 0.f; }
  float m_run = -1e30f, l_run = 0.f;

  const int ntiles = 2 * qb + 2;
  for (int kt = 0; kt < ntiles; ++kt) {
    const int k0 = kt * 64;
    __syncthreads();   // prior tile's LDS reads done
    // ---- stage K tile (rows=key) and V^T tile (rows=d) via gload_lds ----
    #pragma unroll
    for (int i = 0; i < 2; ++i) {
      const int c = i * 256 + wid * 64 + lane;   // linear chunk 0..511
      const int r = c >> 3, sg = c & 7, js = sg ^ (r & 7);
      GLOAD16(K + base + (k0 + r) * HD + js * 8, Ks + i * 4096 + wid * 1024);
      GLOAD16(V + base + r * T_SEQ + k0 + js * 8, Vs + i * 4096 + wid * 1024);
    }
    __syncthreads();   // compiler drains vmcnt before barrier

    if (k0 <= qw + 31) {   // wave-uniform: any unmasked work in this tile?
      // ---- S^T = K Q^T : two 32-key blocks ----
      f32x16 s0, s1;
      #pragma unroll
      for (int r = 0; r < 16; ++r) { s0[r] = 0.f; s1[r] = 0.f; }
      #pragma unroll
      for (int ds = 0; ds < 4; ++ds) {
        const int sg = ds * 2 + hi;
        const int key0 = l31, key1 = 32 + l31;
        const bf16x8 kf0 = *(const bf16x8*)(Ks + key0 * 128 + ((sg ^ (key0 & 7)) << 4));
        const bf16x8 kf1 = *(const bf16x8*)(Ks + key1 * 128 + ((sg ^ (key1 & 7)) << 4));
        s0 = mfma32(kf0, qfr[ds], s0);
        s1 = mfma32(kf1, qfr[ds], s1);
      }

      // ---- causal mask (diagonal tiles only) ----
      if (k0 + 63 > qw) {
        #pragma unroll
        for (int r = 0; r < 16; ++r) {
          const int kr = (r & 3) + 8 * (r >> 2) + 4 * hi;
          if (k0 + kr > q)      s0[r] = -1e30f;
          if (k0 + 32 + kr > q) s1[r] = -1e30f;
        }
      }

      // ---- lane-local online softmax with defer-max (T13, THR=8) ----
      float mx = s0[0];
      #pragma unroll
      for (int r = 1; r < 16; ++r) mx = fmaxf(mx, s0[r]);
      #pragma unroll
      for (int r = 0; r < 16; ++r) mx = fmaxf(mx, s1[r]);
      mx = fmaxf(mx, __shfl_xor(mx, 32));
      if (!__all(mx <= m_run + 8.0f)) {   // rescale only when max grew
        const float mnew = fmaxf(m_run, mx);
        const float alpha = __expf(m_run - mnew);
        m_run = mnew;
        l_run *= alpha;
        #pragma unroll
        for (int r = 0; r < 16; ++r) { o[0][r] *= alpha; o[1][r] *= alpha; }
      }
      float sumA = 0.f, sumB = 0.f;
      #pragma unroll
      for (int r = 0; r < 16; ++r) {
        s0[r] = __expf(s0[r] - m_run); sumA += s0[r];
        s1[r] = __expf(s1[r] - m_run); sumB += s1[r];
      }
      float sum = sumA + sumB;
      sum += __shfl_xor(sum, 32);
      l_run += sum;

      // ---- P -> bf16 A/B-frag in-register, then O^T += V^T P^T ----
      #pragma unroll
      for (int ks = 0; ks < 4; ++ks) {
        const f32x16 pt = (ks < 2) ? s0 : s1;
        const int m = 8 * (ks & 1);
        unsigned wA = packpair(pt[m + 0], pt[m + 1]);
        unsigned wB = packpair(pt[m + 2], pt[m + 3]);
        unsigned wC = packpair(pt[m + 4], pt[m + 5]);
        unsigned wD = packpair(pt[m + 6], pt[m + 7]);
        PLSWAP(wA, wC);   // -> wA = W0, wC = W2
        PLSWAP(wB, wD);   // -> wB = W1, wD = W3
        uint4 uw; uw.x = wA; uw.y = wB; uw.z = wC; uw.w = wD;
        const bf16x8 pf = __builtin_bit_cast(bf16x8, uw);
        #pragma unroll
        for (int db = 0; db < 2; ++db) {
          const int d = db * 32 + l31;
          const int sg = ks * 2 + hi;
          const bf16x8 vf = *(const bf16x8*)(Vs + d * 128 + ((sg ^ (d & 7)) << 4));
          o[db] = mfma32(vf, pf, o[db]);
        }
      }
    }
  }

  // ---- epilogue: O^T/l -> AO (B,H,T,hd) ----
  const float inv = 1.f / l_run;
  #pragma unroll
  for (int db = 0; db < 2; ++db)
    #pragma unroll
    for (int t = 0; t < 4; ++t) {
      ushort4 pk;
      pk.x = f2b(o[db][4 * t + 0] * inv);
      pk.y = f2b(o[db][4 * t + 1] * inv);
      pk.z = f2b(o[db][4 * t + 2] * inv);
      pk.w = f2b(o[db][4 * t + 3] * inv);
      const int d = db * 32 + 8 * t + 4 * hi;
      *(ushort4*)(AO + base + q * HD + d) = pk;
    }
}

// ======================================================================
extern "C" void kernel_launch(void* const* d_in, const int* in_sizes, int n_in,
                              void* d_out, int out_size, void* d_ws, size_t ws_size,
                              hipStream_t stream) {
  const float* x  = (const float*)d_in[0];
  const float* wq = (const float*)d_in[1];
  const float* wk = (const float*)d_in[2];
  const float* wv = (const float*)d_in[3];
  const float* wo = (const float*)d_in[4];
  const float* fc = (const float*)d_in[5];
  float* out = (float*)d_out;

  const int ME = 1 << 20;
  unsigned short* W    = (unsigned short*)d_ws;
  unsigned short* xb   = W;               // 4M  x bf16
  unsigned short* wqkv = W + 4 * ME;      // 3M  [wq;wk;wv] bf16
  unsigned short* wob  = W + 7 * ME;      // 1M
  unsigned short* Qb   = W + 8 * ME;      // 4M  (B,H,T,hd), pre-scaled+RoPE'd
  unsigned short* Kb   = W + 12 * ME;     // 4M  (B,H,T,hd), RoPE'd
  unsigned short* Vt   = W + 16 * ME;     // 4M  (B,H,hd,T)
  unsigned short* AO   = W + 20 * ME;     // 4M  (B,H,T,hd)

  // ---- fp32 -> bf16 (single fused kernel) ----
  hipLaunchKernelGGL(cvt_all, dim3(8192), dim3(256), 0, stream,
                     x, wq, wk, wv, wo, xb, wqkv, wob);

  // ---- fused QKV projection + RoPE + Q pre-scale ----
  hipLaunchKernelGGL((gemm_bf16<0, 3>), dim3(24, 32), dim3(256), 0, stream,
                     xb, wqkv, Qb, Vt, (float*)nullptr, fc, 4096, 3072, 1024);

  // ---- attention ----
  hipLaunchKernelGGL(attn_kernel, dim3(512), dim3(256), 0, stream, Qb, Kb, Vt, AO);

  // ---- output projection ----
  hipLaunchKernelGGL((gemm_bf16<1, 0>), dim3(8, 32), dim3(256), 0, stream,
                     AO, wob, (unsigned short*)nullptr, (unsigned short*)nullptr,
                     out, (const float*)nullptr, 4096, 1024, 1024);
}